// Round 15
// baseline (211.667 us; speedup 1.0000x reference)
//
#include <hip/hip_runtime.h>

// NAM: out[b,c] = bias[c] + sum_f Wout[f]^T · relu(W2[f]^T · relu(x[b,f]*W1[f] + b1[f]) + b2[f])
// B=8192, F=256, H1=64, H2=32, C=10. fp32 (no fp32-input MFMA on CDNA4).
//
// R14: (1) chunked-h2 core — o processed in 2 chunks of 16, h1 recomputed per chunk
// (+5% ops) -> live set ~35 regs, true VGPR fit, no AGPR round-trips (R13: VGPR=28 +
// AGPR shadow = 1.34x busy inflation, 51% occupancy). (2) two-stage reduce — R13's
// hidden 50µs was nam_reduce4's 80 blocks x 128 serial strided loads (1.25 waves/CU,
// latency-bound). Now 64->8 (640 blocks) then 8->out (80 blocks).

#define NB 8192
#define NF 256
#define H1 64
#define H2 32
#define NC 10
#define THREADS 256
#define TS 64                    // transpose tile
#define FPG 4                    // features per block
#define NFG (NF / FPG)           // 64 partial groups
#define GC 8                     // reduce stage-A output chunks

// ---- x[B][F] -> xT[F][B], LDS-tiled, fully coalesced both sides ----
__global__ __launch_bounds__(256) void nam_transpose(const float* __restrict__ x,
                                                     float* __restrict__ xT) {
    __shared__ float tile[TS][TS + 1];
    const int t  = threadIdx.x;
    const int c0 = t & 63;
    const int r0 = t >> 6;
    const int bb = blockIdx.x * TS;
    const int fb = blockIdx.y * TS;
#pragma unroll
    for (int k = 0; k < 16; ++k) {
        const int r = r0 + k * 4;
        tile[r][c0] = x[(size_t)(bb + r) * NF + fb + c0];
    }
    __syncthreads();
#pragma unroll
    for (int k = 0; k < 16; ++k) {
        const int r = r0 + k * 4;
        xT[(size_t)(fb + r) * NB + bb + c0] = tile[c0][r];
    }
}

// ---- main: one thread = 1 row x FPG features; o-dim in 2 chunks of 16 ----
__global__ __launch_bounds__(THREADS) void nam_core_v3(
    const float* __restrict__ xT, const float* __restrict__ W1,
    const float* __restrict__ b1, const float* __restrict__ W2,
    const float* __restrict__ b2, const float* __restrict__ Wout,
    float* __restrict__ partial) {   // [NFG][NC][NB]
    const int fg = blockIdx.x;       // fastest dim -> XCD = fg % 8 (weight L2 locality)
    const int rg = blockIdx.y;
    const int b  = rg * THREADS + threadIdx.x;
    const int f0 = fg * FPG;

    float acc[NC];
#pragma unroll
    for (int c = 0; c < NC; ++c) acc[c] = 0.f;

#pragma unroll 1   // keep body I$-resident
    for (int ff = 0; ff < FPG; ++ff) {
        const int f = f0 + ff;
        const float xv = xT[(size_t)f * NB + b];   // coalesced, L2-resident
        // Wave-uniform weight pointers -> s_load streams, SGPR operands in v_fma.
        const float* __restrict__ W1f = W1 + (size_t)f * H1;
        const float* __restrict__ b1f = b1 + (size_t)f * H1;
        const float* __restrict__ W2f = W2 + (size_t)f * (H1 * H2);
        const float* __restrict__ b2f = b2 + (size_t)f * H2;
        const float* __restrict__ Wof = Wout + (size_t)f * (H2 * NC);

#pragma unroll     // 2 chunks, fully static: h2 lives in 16 VGPRs per chunk
        for (int ch = 0; ch < 2; ++ch) {
            const int ob = ch * 16;
            float h2[16];
#pragma unroll
            for (int o = 0; o < 16; ++o) h2[o] = b2f[ob + o];

#pragma unroll 8   // batches s_load_dwordx16 ahead of the FMA runs
            for (int hh = 0; hh < H1; ++hh) {
                const float a = fmaxf(fmaf(xv, W1f[hh], b1f[hh]), 0.f);  // recomputed/chunk
                const float* wr = W2f + (size_t)hh * H2 + ob;
#pragma unroll
                for (int o = 0; o < 16; ++o)
                    h2[o] = fmaf(a, wr[o], h2[o]);   // v_fmac v,v,s
            }

#pragma unroll 8
            for (int o = 0; o < 16; ++o) {
                const float g = fmaxf(h2[o], 0.f);
                const float* wo = Wof + (size_t)(ob + o) * NC;
#pragma unroll
                for (int c = 0; c < NC; ++c)
                    acc[c] = fmaf(g, wo[c], acc[c]);
            }
        }
    }

    // [G][NC][NB]: lane-consecutive b -> 10 coalesced 256B/wave stores.
#pragma unroll
    for (int c = 0; c < NC; ++c)
        partial[((size_t)fg * NC + c) * NB + b] = acc[c];
}

// ---- reduce stage A: [NFG][NC][NB] -> [GC][NC][NB]; 8 loads/thread, 640 blocks ----
__global__ __launch_bounds__(256) void nam_reduceA(const float* __restrict__ part,
                                                   float* __restrict__ mid) {
    const int i = blockIdx.x * 256 + threadIdx.x;   // over GC * NC * NB/4
    const int chunk = i / (NC * NB / 4);
    const int j     = i % (NC * NB / 4);
    const int c  = j / (NB / 4);
    const int b4 = j % (NB / 4);
    float4 s = {0.f, 0.f, 0.f, 0.f};
#pragma unroll
    for (int g = 0; g < NFG / GC; ++g) {            // 8 independent loads -> pipelined
        const float4 v =
            ((const float4*)(part + ((size_t)(chunk * (NFG / GC) + g) * NC + c) * NB))[b4];
        s.x += v.x; s.y += v.y; s.z += v.z; s.w += v.w;
    }
    ((float4*)(mid + ((size_t)chunk * NC + c) * NB))[b4] = s;
}

// ---- reduce stage B: [GC][NC][NB] + bias -> out[NB][NC] ----
__global__ __launch_bounds__(256) void nam_reduceB(const float* __restrict__ mid,
                                                   const float* __restrict__ bias,
                                                   float* __restrict__ out) {
    const int i  = blockIdx.x * 256 + threadIdx.x;   // over NC * NB/4 = 20480
    const int c  = i / (NB / 4);
    const int b4 = i % (NB / 4);
    const float bc = bias[c];
    float4 s = {bc, bc, bc, bc};
#pragma unroll
    for (int g = 0; g < GC; ++g) {
        const float4 v = ((const float4*)(mid + ((size_t)g * NC + c) * NB))[b4];
        s.x += v.x; s.y += v.y; s.z += v.z; s.w += v.w;
    }
    const int b = 4 * b4;
    out[(size_t)(b + 0) * NC + c] = s.x;
    out[(size_t)(b + 1) * NC + c] = s.y;
    out[(size_t)(b + 2) * NC + c] = s.z;
    out[(size_t)(b + 3) * NC + c] = s.w;
}

// ---- last-resort fallback (tiny ws): direct x reads + atomics ----
__global__ __launch_bounds__(256) void nam_init_out(const float* __restrict__ bias,
                                                    float* __restrict__ out) {
    const int i = blockIdx.x * 256 + threadIdx.x;
    if (i < NB * NC) out[i] = bias[i % NC];
}

__global__ __launch_bounds__(256) void nam_fallback(
    const float* __restrict__ x,  const float* __restrict__ W1,
    const float* __restrict__ b1, const float* __restrict__ W2,
    const float* __restrict__ b2, const float* __restrict__ Wout,
    float* __restrict__ out) {
    const int b  = blockIdx.x * 256 + threadIdx.x;
    const int f0 = blockIdx.y * 16;
    float acc[NC];
#pragma unroll
    for (int c = 0; c < NC; ++c) acc[c] = 0.f;
#pragma unroll 1
    for (int ff = 0; ff < 16; ++ff) {
        const int f = f0 + ff;
        const float xv = x[(size_t)b * NF + f];
        const float* W1f = W1 + (size_t)f * H1;
        const float* b1f = b1 + (size_t)f * H1;
        const float* W2f = W2 + (size_t)f * (H1 * H2);
        const float* b2f = b2 + (size_t)f * H2;
        const float* Wof = Wout + (size_t)f * (H2 * NC);
#pragma unroll
        for (int ch = 0; ch < 2; ++ch) {
            const int ob = ch * 16;
            float h2[16];
#pragma unroll
            for (int o = 0; o < 16; ++o) h2[o] = b2f[ob + o];
#pragma unroll 8
            for (int hh = 0; hh < H1; ++hh) {
                const float a = fmaxf(fmaf(xv, W1f[hh], b1f[hh]), 0.f);
                const float* wr = W2f + (size_t)hh * H2 + ob;
#pragma unroll
                for (int o = 0; o < 16; ++o) h2[o] = fmaf(a, wr[o], h2[o]);
            }
#pragma unroll
            for (int o = 0; o < 16; ++o) {
                const float g = fmaxf(h2[o], 0.f);
                const float* wo = Wof + (size_t)(ob + o) * NC;
#pragma unroll
                for (int c = 0; c < NC; ++c) acc[c] = fmaf(g, wo[c], acc[c]);
            }
        }
    }
    float* orow = out + (size_t)b * NC;
#pragma unroll
    for (int c = 0; c < NC; ++c) atomicAdd(&orow[c], acc[c]);
}

extern "C" void kernel_launch(void* const* d_in, const int* in_sizes, int n_in,
                              void* d_out, int out_size, void* d_ws, size_t ws_size,
                              hipStream_t stream) {
    const float* x    = (const float*)d_in[0];
    const float* W1   = (const float*)d_in[1];
    const float* b1   = (const float*)d_in[2];
    const float* W2   = (const float*)d_in[3];
    const float* b2   = (const float*)d_in[4];
    const float* Wout = (const float*)d_in[5];
    const float* bias = (const float*)d_in[6];
    float* out = (float*)d_out;

    // ws layout: [xT: NF*NB][part: NFG*NC*NB][mid: GC*NC*NB] = 8.4 + 21.0 + 2.6 = 32 MB
    float* xT   = (float*)d_ws;
    float* part = xT + (size_t)NF * NB;
    float* mid  = part + (size_t)NFG * NC * NB;
    const size_t need =
        ((size_t)NF * NB + (size_t)NFG * NC * NB + (size_t)GC * NC * NB) * sizeof(float);

    if (ws_size >= need) {   // R12 proved ws >= 50.3 MB, need = 32 MB
        nam_transpose<<<dim3(NB / TS, NF / TS), 256, 0, stream>>>(x, xT);
        nam_core_v3<<<dim3(NFG, NB / THREADS), THREADS, 0, stream>>>(
            xT, W1, b1, W2, b2, Wout, part);
        nam_reduceA<<<GC * (NC * NB / 4) / 256, 256, 0, stream>>>(part, mid);
        nam_reduceB<<<(NC * NB / 4) / 256, 256, 0, stream>>>(mid, bias, out);
    } else {
        nam_init_out<<<(NB * NC + 255) / 256, 256, 0, stream>>>(bias, out);
        nam_fallback<<<dim3(NB / 256, 16), 256, 0, stream>>>(x, W1, b1, W2, b2, Wout, out);
    }
}

// Round 16
// 200.612 us; speedup vs baseline: 1.0551x; 1.0551x over previous
//
#include <hip/hip_runtime.h>

// NAM: out[b,c] = bias[c] + sum_f Wout[f]^T · relu(W2[f]^T · relu(x[b,f]*W1[f] + b1[f]) + b2[f])
// B=8192, F=256, H1=64, H2=32, C=10. fp32 (no fp32-input MFMA on CDNA4).
//
// R16: best measured core (R13: whole h2[32], launch_bounds(256) plain, 122µs @ 73%
// VALUBusy) + two fixes: (1) xv loads hoisted to kernel entry via 4x unrolled feature
// bodies (R13's '#pragma unroll 1' re-loaded xv per iteration -> vmcnt bubble);
// (2) two-stage reduce 64->8->out (R13's 80-block 128-deep serial reduce was ~50µs).
// R15 lesson: h2-chunking regressed (compiler AGPR-parks regardless; +10% recompute).

#define NB 8192
#define NF 256
#define H1 64
#define H2 32
#define NC 10
#define THREADS 256
#define TS 64                    // transpose tile
#define FPG 4                    // features per block
#define NFG (NF / FPG)           // 64 partial groups
#define GC 8                     // reduce stage-A output chunks

// ---- x[B][F] -> xT[F][B], LDS-tiled, fully coalesced both sides ----
__global__ __launch_bounds__(256) void nam_transpose(const float* __restrict__ x,
                                                     float* __restrict__ xT) {
    __shared__ float tile[TS][TS + 1];
    const int t  = threadIdx.x;
    const int c0 = t & 63;
    const int r0 = t >> 6;
    const int bb = blockIdx.x * TS;
    const int fb = blockIdx.y * TS;
#pragma unroll
    for (int k = 0; k < 16; ++k) {
        const int r = r0 + k * 4;
        tile[r][c0] = x[(size_t)(bb + r) * NF + fb + c0];
    }
    __syncthreads();
#pragma unroll
    for (int k = 0; k < 16; ++k) {
        const int r = r0 + k * 4;
        xT[(size_t)(fb + r) * NB + bb + c0] = tile[c0][r];
    }
}

// ---- main: one thread = 1 row x 4 features; xv hoisted; weights via s_load ----
__global__ __launch_bounds__(THREADS) void nam_core_v4(
    const float* __restrict__ xT, const float* __restrict__ W1,
    const float* __restrict__ b1, const float* __restrict__ W2,
    const float* __restrict__ b2, const float* __restrict__ Wout,
    float* __restrict__ partial) {   // [NFG][NC][NB]
    const int fg = blockIdx.x;       // fastest dim -> XCD = fg % 8 (weight L2 locality)
    const int rg = blockIdx.y;
    const int b  = rg * THREADS + threadIdx.x;
    const int f0 = fg * FPG;

    // All 4 x-values loaded up front (coalesced, independent -> one vmcnt drain).
    const float xv0 = xT[(size_t)(f0 + 0) * NB + b];
    const float xv1 = xT[(size_t)(f0 + 1) * NB + b];
    const float xv2 = xT[(size_t)(f0 + 2) * NB + b];
    const float xv3 = xT[(size_t)(f0 + 3) * NB + b];

    float acc[NC];
#pragma unroll
    for (int c = 0; c < NC; ++c) acc[c] = 0.f;

    // R13's proven body: whole h2[32], unroll-8 hh (s_load_dwordx16 batches).
    auto do_feature = [&](const int f, const float xv) {
        const float* __restrict__ W1f = W1 + (size_t)f * H1;
        const float* __restrict__ b1f = b1 + (size_t)f * H1;
        const float* __restrict__ W2f = W2 + (size_t)f * (H1 * H2);
        const float* __restrict__ b2f = b2 + (size_t)f * H2;
        const float* __restrict__ Wof = Wout + (size_t)f * (H2 * NC);

        float h2[H2];
#pragma unroll
        for (int o = 0; o < H2; ++o) h2[o] = b2f[o];

#pragma unroll 8
        for (int hh = 0; hh < H1; ++hh) {
            const float a = fmaxf(fmaf(xv, W1f[hh], b1f[hh]), 0.f);
            const float* wr = W2f + (size_t)hh * H2;
#pragma unroll
            for (int o = 0; o < H2; ++o)
                h2[o] = fmaf(a, wr[o], h2[o]);   // v_fmac v,v,s
        }

#pragma unroll 8
        for (int o = 0; o < H2; ++o) {
            const float g = fmaxf(h2[o], 0.f);
            const float* wo = Wof + o * NC;
#pragma unroll
            for (int c = 0; c < NC; ++c)
                acc[c] = fmaf(g, wo[c], acc[c]);
        }
    };

    do_feature(f0 + 0, xv0);
    do_feature(f0 + 1, xv1);
    do_feature(f0 + 2, xv2);
    do_feature(f0 + 3, xv3);

    // [G][NC][NB]: lane-consecutive b -> 10 coalesced 256B/wave stores.
#pragma unroll
    for (int c = 0; c < NC; ++c)
        partial[((size_t)fg * NC + c) * NB + b] = acc[c];
}

// ---- reduce stage A: [NFG][NC][NB] -> [GC][NC][NB]; 8 loads/thread, 640 blocks ----
__global__ __launch_bounds__(256) void nam_reduceA(const float* __restrict__ part,
                                                   float* __restrict__ mid) {
    const int i = blockIdx.x * 256 + threadIdx.x;   // over GC * NC * NB/4
    const int chunk = i / (NC * NB / 4);
    const int j     = i % (NC * NB / 4);
    const int c  = j / (NB / 4);
    const int b4 = j % (NB / 4);
    float4 s = {0.f, 0.f, 0.f, 0.f};
#pragma unroll
    for (int g = 0; g < NFG / GC; ++g) {            // 8 independent loads -> pipelined
        const float4 v =
            ((const float4*)(part + ((size_t)(chunk * (NFG / GC) + g) * NC + c) * NB))[b4];
        s.x += v.x; s.y += v.y; s.z += v.z; s.w += v.w;
    }
    ((float4*)(mid + ((size_t)chunk * NC + c) * NB))[b4] = s;
}

// ---- reduce stage B: [GC][NC][NB] + bias -> out[NB][NC] ----
__global__ __launch_bounds__(256) void nam_reduceB(const float* __restrict__ mid,
                                                   const float* __restrict__ bias,
                                                   float* __restrict__ out) {
    const int i  = blockIdx.x * 256 + threadIdx.x;   // over NC * NB/4 = 20480
    const int c  = i / (NB / 4);
    const int b4 = i % (NB / 4);
    const float bc = bias[c];
    float4 s = {bc, bc, bc, bc};
#pragma unroll
    for (int g = 0; g < GC; ++g) {
        const float4 v = ((const float4*)(mid + ((size_t)g * NC + c) * NB))[b4];
        s.x += v.x; s.y += v.y; s.z += v.z; s.w += v.w;
    }
    const int b = 4 * b4;
    out[(size_t)(b + 0) * NC + c] = s.x;
    out[(size_t)(b + 1) * NC + c] = s.y;
    out[(size_t)(b + 2) * NC + c] = s.z;
    out[(size_t)(b + 3) * NC + c] = s.w;
}

// ---- last-resort fallback (tiny ws): direct x reads + atomics ----
__global__ __launch_bounds__(256) void nam_init_out(const float* __restrict__ bias,
                                                    float* __restrict__ out) {
    const int i = blockIdx.x * 256 + threadIdx.x;
    if (i < NB * NC) out[i] = bias[i % NC];
}

__global__ __launch_bounds__(256) void nam_fallback(
    const float* __restrict__ x,  const float* __restrict__ W1,
    const float* __restrict__ b1, const float* __restrict__ W2,
    const float* __restrict__ b2, const float* __restrict__ Wout,
    float* __restrict__ out) {
    const int b  = blockIdx.x * 256 + threadIdx.x;
    const int f0 = blockIdx.y * 16;
    float acc[NC];
#pragma unroll
    for (int c = 0; c < NC; ++c) acc[c] = 0.f;
#pragma unroll 1
    for (int ff = 0; ff < 16; ++ff) {
        const int f = f0 + ff;
        const float xv = x[(size_t)b * NF + f];
        const float* W1f = W1 + (size_t)f * H1;
        const float* b1f = b1 + (size_t)f * H1;
        const float* W2f = W2 + (size_t)f * (H1 * H2);
        const float* b2f = b2 + (size_t)f * H2;
        const float* Wof = Wout + (size_t)f * (H2 * NC);
        float h2[H2];
#pragma unroll
        for (int o = 0; o < H2; ++o) h2[o] = b2f[o];
#pragma unroll 8
        for (int hh = 0; hh < H1; ++hh) {
            const float a = fmaxf(fmaf(xv, W1f[hh], b1f[hh]), 0.f);
            const float* wr = W2f + (size_t)hh * H2;
#pragma unroll
            for (int o = 0; o < H2; ++o) h2[o] = fmaf(a, wr[o], h2[o]);
        }
#pragma unroll
        for (int o = 0; o < H2; ++o) {
            const float g = fmaxf(h2[o], 0.f);
            const float* wo = Wof + o * NC;
#pragma unroll
            for (int c = 0; c < NC; ++c) acc[c] = fmaf(g, wo[c], acc[c]);
        }
    }
    float* orow = out + (size_t)b * NC;
#pragma unroll
    for (int c = 0; c < NC; ++c) atomicAdd(&orow[c], acc[c]);
}

extern "C" void kernel_launch(void* const* d_in, const int* in_sizes, int n_in,
                              void* d_out, int out_size, void* d_ws, size_t ws_size,
                              hipStream_t stream) {
    const float* x    = (const float*)d_in[0];
    const float* W1   = (const float*)d_in[1];
    const float* b1   = (const float*)d_in[2];
    const float* W2   = (const float*)d_in[3];
    const float* b2   = (const float*)d_in[4];
    const float* Wout = (const float*)d_in[5];
    const float* bias = (const float*)d_in[6];
    float* out = (float*)d_out;

    // ws layout: [xT: 8.4MB][part: 21.0MB][mid: 2.6MB] = 32 MB (R12 proved ws >= 50.3MB)
    float* xT   = (float*)d_ws;
    float* part = xT + (size_t)NF * NB;
    float* mid  = part + (size_t)NFG * NC * NB;
    const size_t need =
        ((size_t)NF * NB + (size_t)NFG * NC * NB + (size_t)GC * NC * NB) * sizeof(float);

    if (ws_size >= need) {
        nam_transpose<<<dim3(NB / TS, NF / TS), 256, 0, stream>>>(x, xT);
        nam_core_v4<<<dim3(NFG, NB / THREADS), THREADS, 0, stream>>>(
            xT, W1, b1, W2, b2, Wout, part);
        nam_reduceA<<<GC * (NC * NB / 4) / 256, 256, 0, stream>>>(part, mid);
        nam_reduceB<<<(NC * NB / 4) / 256, 256, 0, stream>>>(mid, bias, out);
    } else {
        nam_init_out<<<(NB * NC + 255) / 256, 256, 0, stream>>>(bias, out);
        nam_fallback<<<dim3(NB / 256, 16), 256, 0, stream>>>(x, W1, b1, W2, b2, Wout, out);
    }
}